// Round 1
// baseline (51.133 us; speedup 1.0000x reference)
//
#include <hip/hip_runtime.h>

// hinge one-vs-rest loss:
//   loss = sum_c mean_b max(1 - outputs*sign(labels), 0)
//        = (1/B) * sum_{all elements} max(1 - o*s, 0),  B = 16384
// Pure streaming reduction: 131 MB read -> scalar. Memory-bound; target HBM BW.

__global__ __launch_bounds__(256) void hinge_onevsrest_reduce_kernel(
    const float4* __restrict__ out4,
    const float4* __restrict__ lab4,
    float* __restrict__ loss,
    int n4, float inv_b)
{
    float acc = 0.0f;
    const int stride = gridDim.x * blockDim.x;
    for (int i = blockIdx.x * blockDim.x + threadIdx.x; i < n4; i += stride) {
        const float4 o = out4[i];
        const float4 l = lab4[i];
        // sign(label): +1 if l >= 0 else -1; hinge = max(1 - o*sign, 0)
        acc += fmaxf(1.0f - (l.x >= 0.0f ? o.x : -o.x), 0.0f);
        acc += fmaxf(1.0f - (l.y >= 0.0f ? o.y : -o.y), 0.0f);
        acc += fmaxf(1.0f - (l.z >= 0.0f ? o.z : -o.z), 0.0f);
        acc += fmaxf(1.0f - (l.w >= 0.0f ? o.w : -o.w), 0.0f);
    }

    // wave-64 butterfly/shfl_down reduction
    #pragma unroll
    for (int off = 32; off > 0; off >>= 1)
        acc += __shfl_down(acc, off, 64);

    __shared__ float wave_sums[4];  // 256 threads / 64 lanes
    const int lane = threadIdx.x & 63;
    const int wid  = threadIdx.x >> 6;
    if (lane == 0) wave_sums[wid] = acc;
    __syncthreads();

    if (threadIdx.x == 0) {
        const float s = wave_sums[0] + wave_sums[1] + wave_sums[2] + wave_sums[3];
        atomicAdd(loss, s * inv_b);  // one device-scope atomic per block
    }
}

extern "C" void kernel_launch(void* const* d_in, const int* in_sizes, int n_in,
                              void* d_out, int out_size, void* d_ws, size_t ws_size,
                              hipStream_t stream) {
    const float* outputs = (const float*)d_in[0];
    const float* labels  = (const float*)d_in[1];
    float* loss = (float*)d_out;

    const long long n = (long long)in_sizes[0];   // 16384000, divisible by 4
    const int n4 = (int)(n / 4);
    const float inv_b = 1.0f / 16384.0f;

    // d_out is poisoned once and never re-poisoned; we accumulate with atomics,
    // so zero it every call (deterministic, graph-capture-safe).
    hipMemsetAsync(d_out, 0, sizeof(float), stream);

    const int block = 256;
    int grid = (n4 + block - 1) / block;
    if (grid > 2048) grid = 2048;   // 256 CU x 8 blocks, grid-stride the rest

    hinge_onevsrest_reduce_kernel<<<grid, block, 0, stream>>>(
        (const float4*)outputs, (const float4*)labels, loss, n4, inv_b);
}

// Round 2
// 50.529 us; speedup vs baseline: 1.0119x; 1.0119x over previous
//
#include <hip/hip_runtime.h>

// hinge one-vs-rest loss:
//   loss = (1/B) * sum_{all elements} max(1 - o*sign(l), 0),  B = 16384
// Streaming reduction over 131 MB (L3-resident on replay). R1 showed
// latency-bound (VALUBusy 4.5%, eff BW 2.6 TB/s): only 2 loads in flight
// per thread. Fix: 8x unroll -> 16 independent float4 loads per thread.

constexpr int BLOCK  = 256;
constexpr int UNROLL = 8;   // float4 per thread per array
constexpr int TILE   = BLOCK * UNROLL;  // 2048 float4 per block

__global__ __launch_bounds__(BLOCK) void hinge_onevsrest_reduce_kernel(
    const float4* __restrict__ out4,
    const float4* __restrict__ lab4,
    float* __restrict__ loss,
    int n4, float inv_b)
{
    const int tid = threadIdx.x;
    float acc = 0.0f;

    // Block-tiled, grid covers all tiles exactly when n4 % TILE == 0
    // (16384*1000/4 = 4,096,000 = 2000 * 2048). Guards are no-ops then.
    const long long base = (long long)blockIdx.x * TILE + tid;

    float4 o[UNROLL], l[UNROLL];
    // Issue all 16 loads back-to-back: max memory-level parallelism.
    #pragma unroll
    for (int u = 0; u < UNROLL; ++u) {
        const long long idx = base + (long long)u * BLOCK;
        if (idx < n4) o[u] = out4[idx];
    }
    #pragma unroll
    for (int u = 0; u < UNROLL; ++u) {
        const long long idx = base + (long long)u * BLOCK;
        if (idx < n4) l[u] = lab4[idx];
    }
    #pragma unroll
    for (int u = 0; u < UNROLL; ++u) {
        const long long idx = base + (long long)u * BLOCK;
        if (idx < n4) {
            acc += fmaxf(1.0f - (l[u].x >= 0.0f ? o[u].x : -o[u].x), 0.0f);
            acc += fmaxf(1.0f - (l[u].y >= 0.0f ? o[u].y : -o[u].y), 0.0f);
            acc += fmaxf(1.0f - (l[u].z >= 0.0f ? o[u].z : -o[u].z), 0.0f);
            acc += fmaxf(1.0f - (l[u].w >= 0.0f ? o[u].w : -o[u].w), 0.0f);
        }
    }

    // wave-64 reduction
    #pragma unroll
    for (int off = 32; off > 0; off >>= 1)
        acc += __shfl_down(acc, off, 64);

    __shared__ float wave_sums[BLOCK / 64];
    const int lane = tid & 63;
    const int wid  = tid >> 6;
    if (lane == 0) wave_sums[wid] = acc;
    __syncthreads();

    if (tid == 0) {
        float s = 0.0f;
        #pragma unroll
        for (int w = 0; w < BLOCK / 64; ++w) s += wave_sums[w];
        atomicAdd(loss, s * inv_b);  // one device-scope atomic per block
    }
}

extern "C" void kernel_launch(void* const* d_in, const int* in_sizes, int n_in,
                              void* d_out, int out_size, void* d_ws, size_t ws_size,
                              hipStream_t stream) {
    const float* outputs = (const float*)d_in[0];
    const float* labels  = (const float*)d_in[1];
    float* loss = (float*)d_out;

    const long long n = (long long)in_sizes[0];   // 16,384,000 (divisible by 4)
    const int n4 = (int)(n / 4);                  // 4,096,000
    const float inv_b = 1.0f / 16384.0f;

    // Output is accumulated via atomics; zero it every call.
    hipMemsetAsync(d_out, 0, sizeof(float), stream);

    const int grid = (n4 + TILE - 1) / TILE;      // 2000 blocks, exact

    hinge_onevsrest_reduce_kernel<<<grid, BLOCK, 0, stream>>>(
        (const float4*)outputs, (const float4*)labels, loss, n4, inv_b);
}

// Round 3
// 28.311 us; speedup vs baseline: 1.8061x; 1.7848x over previous
//
#include <hip/hip_runtime.h>

// hinge one-vs-rest loss:
//   loss = (1/B) * sum_{all elements} max(1 - o*sign(l), 0),  B = 16384
// R1/R2 post-mortem: two different load structures both landed at ~51 us and
// scaled with the number of same-address atomicAdds (2048 vs 2000) -> the
// dispatch was serialization-bound on device-scope float atomics to one
// address, NOT memory-bound. Fix: two-stage reduction, zero atomics.

constexpr int BLOCK  = 256;
constexpr int UNROLL = 8;               // float4 per thread per array
constexpr int TILE   = BLOCK * UNROLL;  // 2048 float4 per block

__device__ __forceinline__ float block_reduce(float acc, float* wave_sums) {
    #pragma unroll
    for (int off = 32; off > 0; off >>= 1)
        acc += __shfl_down(acc, off, 64);
    const int lane = threadIdx.x & 63;
    const int wid  = threadIdx.x >> 6;
    if (lane == 0) wave_sums[wid] = acc;
    __syncthreads();
    float s = 0.0f;
    #pragma unroll
    for (int w = 0; w < BLOCK / 64; ++w) s += wave_sums[w];
    return s;
}

// Stage 1: per-block partial sums -> d_ws (plain stores, no atomics).
__global__ __launch_bounds__(BLOCK) void hinge_stage1_kernel(
    const float4* __restrict__ out4,
    const float4* __restrict__ lab4,
    float* __restrict__ partials,
    int n4)
{
    const int tid = threadIdx.x;
    const long long base = (long long)blockIdx.x * TILE + tid;

    float4 o[UNROLL], l[UNROLL];
    #pragma unroll
    for (int u = 0; u < UNROLL; ++u) {
        const long long idx = base + (long long)u * BLOCK;
        if (idx < n4) o[u] = out4[idx];
    }
    #pragma unroll
    for (int u = 0; u < UNROLL; ++u) {
        const long long idx = base + (long long)u * BLOCK;
        if (idx < n4) l[u] = lab4[idx];
    }

    float acc = 0.0f;
    #pragma unroll
    for (int u = 0; u < UNROLL; ++u) {
        const long long idx = base + (long long)u * BLOCK;
        if (idx < n4) {
            acc += fmaxf(1.0f - (l[u].x >= 0.0f ? o[u].x : -o[u].x), 0.0f);
            acc += fmaxf(1.0f - (l[u].y >= 0.0f ? o[u].y : -o[u].y), 0.0f);
            acc += fmaxf(1.0f - (l[u].z >= 0.0f ? o[u].z : -o[u].z), 0.0f);
            acc += fmaxf(1.0f - (l[u].w >= 0.0f ? o[u].w : -o[u].w), 0.0f);
        }
    }

    __shared__ float wave_sums[BLOCK / 64];
    const float s = block_reduce(acc, wave_sums);
    if (tid == 0) partials[blockIdx.x] = s;
}

// Stage 2: one block reduces the partials and writes the scalar loss.
__global__ __launch_bounds__(BLOCK) void hinge_stage2_kernel(
    const float* __restrict__ partials,
    float* __restrict__ loss,
    int n_partials, float inv_b)
{
    float acc = 0.0f;
    for (int i = threadIdx.x; i < n_partials; i += BLOCK)
        acc += partials[i];
    __shared__ float wave_sums[BLOCK / 64];
    const float s = block_reduce(acc, wave_sums);
    if (threadIdx.x == 0) loss[0] = s * inv_b;  // full overwrite, no memset needed
}

extern "C" void kernel_launch(void* const* d_in, const int* in_sizes, int n_in,
                              void* d_out, int out_size, void* d_ws, size_t ws_size,
                              hipStream_t stream) {
    const float* outputs = (const float*)d_in[0];
    const float* labels  = (const float*)d_in[1];
    float* loss     = (float*)d_out;
    float* partials = (float*)d_ws;   // grid floats (8 KB), written before read

    const long long n = (long long)in_sizes[0];   // 16,384,000
    const int n4 = (int)(n / 4);                  // 4,096,000
    const float inv_b = 1.0f / 16384.0f;

    const int grid = (n4 + TILE - 1) / TILE;      // 2000 blocks, exact tiling

    hinge_stage1_kernel<<<grid, BLOCK, 0, stream>>>(
        (const float4*)outputs, (const float4*)labels, partials, n4);
    hinge_stage2_kernel<<<1, BLOCK, 0, stream>>>(partials, loss, grid, inv_b);
}

// Round 4
// 27.341 us; speedup vs baseline: 1.8702x; 1.0355x over previous
//
#include <hip/hip_runtime.h>

// hinge one-vs-rest loss:
//   loss = (1/B) * sum_{all elements} max(1 - o*sign(l), 0),  B = 16384
// R3 post-mortem: two-stage (no atomics) = 28.3 us. VGPR_Count=28 proves the
// compiler sank the "unrolled" loads back into the loop (guards allowed it) --
// real MLP never materialized. Fix: exact tiling (4,096,000 = 2000*2048), no
// guards, 16 unconditional float4 loads hoisted into registers.

constexpr int BLOCK  = 256;
constexpr int UNROLL = 8;               // float4 per thread per array
constexpr int TILE   = BLOCK * UNROLL;  // 2048 float4 per block

__device__ __forceinline__ float block_reduce(float acc, float* wave_sums) {
    #pragma unroll
    for (int off = 32; off > 0; off >>= 1)
        acc += __shfl_down(acc, off, 64);
    const int lane = threadIdx.x & 63;
    const int wid  = threadIdx.x >> 6;
    if (lane == 0) wave_sums[wid] = acc;
    __syncthreads();
    float s = 0.0f;
    #pragma unroll
    for (int w = 0; w < BLOCK / 64; ++w) s += wave_sums[w];
    return s;
}

// Stage 1 (exact tiling, no guards): per-block partials -> d_ws.
__global__ __launch_bounds__(BLOCK) void hinge_stage1_exact(
    const float4* __restrict__ out4,
    const float4* __restrict__ lab4,
    float* __restrict__ partials)
{
    const int tid = threadIdx.x;
    const size_t base = (size_t)blockIdx.x * TILE + tid;
    const float4* __restrict__ po = out4 + base;
    const float4* __restrict__ pl = lab4 + base;

    // All 16 loads unconditional and up-front: real memory-level parallelism.
    float4 o[UNROLL], l[UNROLL];
    #pragma unroll
    for (int u = 0; u < UNROLL; ++u) o[u] = po[u * BLOCK];
    #pragma unroll
    for (int u = 0; u < UNROLL; ++u) l[u] = pl[u * BLOCK];

    // 4 independent accumulator chains.
    float a0 = 0.f, a1 = 0.f, a2 = 0.f, a3 = 0.f;
    #pragma unroll
    for (int u = 0; u < UNROLL; ++u) {
        a0 += fmaxf(1.0f - (l[u].x >= 0.0f ? o[u].x : -o[u].x), 0.0f);
        a1 += fmaxf(1.0f - (l[u].y >= 0.0f ? o[u].y : -o[u].y), 0.0f);
        a2 += fmaxf(1.0f - (l[u].z >= 0.0f ? o[u].z : -o[u].z), 0.0f);
        a3 += fmaxf(1.0f - (l[u].w >= 0.0f ? o[u].w : -o[u].w), 0.0f);
    }
    float acc = (a0 + a1) + (a2 + a3);

    __shared__ float wave_sums[BLOCK / 64];
    const float s = block_reduce(acc, wave_sums);
    if (tid == 0) partials[blockIdx.x] = s;
}

// Generic guarded fallback (only used if n4 % TILE != 0).
__global__ __launch_bounds__(BLOCK) void hinge_stage1_guarded(
    const float4* __restrict__ out4,
    const float4* __restrict__ lab4,
    float* __restrict__ partials,
    int n4)
{
    const int tid = threadIdx.x;
    const long long base = (long long)blockIdx.x * TILE + tid;
    float acc = 0.0f;
    #pragma unroll
    for (int u = 0; u < UNROLL; ++u) {
        const long long idx = base + (long long)u * BLOCK;
        if (idx < n4) {
            const float4 o = out4[idx];
            const float4 l = lab4[idx];
            acc += fmaxf(1.0f - (l.x >= 0.0f ? o.x : -o.x), 0.0f);
            acc += fmaxf(1.0f - (l.y >= 0.0f ? o.y : -o.y), 0.0f);
            acc += fmaxf(1.0f - (l.z >= 0.0f ? o.z : -o.z), 0.0f);
            acc += fmaxf(1.0f - (l.w >= 0.0f ? o.w : -o.w), 0.0f);
        }
    }
    __shared__ float wave_sums[BLOCK / 64];
    const float s = block_reduce(acc, wave_sums);
    if (tid == 0) partials[blockIdx.x] = s;
}

// Stage 2: one block reduces the partials and writes the scalar loss.
__global__ __launch_bounds__(BLOCK) void hinge_stage2_kernel(
    const float* __restrict__ partials,
    float* __restrict__ loss,
    int n_partials, float inv_b)
{
    float acc = 0.0f;
    for (int i = threadIdx.x; i < n_partials; i += BLOCK)
        acc += partials[i];
    __shared__ float wave_sums[BLOCK / 64];
    const float s = block_reduce(acc, wave_sums);
    if (threadIdx.x == 0) loss[0] = s * inv_b;  // full overwrite
}

extern "C" void kernel_launch(void* const* d_in, const int* in_sizes, int n_in,
                              void* d_out, int out_size, void* d_ws, size_t ws_size,
                              hipStream_t stream) {
    const float* outputs = (const float*)d_in[0];
    const float* labels  = (const float*)d_in[1];
    float* loss     = (float*)d_out;
    float* partials = (float*)d_ws;   // grid floats, written before read

    const long long n = (long long)in_sizes[0];   // 16,384,000
    const int n4 = (int)(n / 4);                  // 4,096,000
    const float inv_b = 1.0f / 16384.0f;

    const int grid = (n4 + TILE - 1) / TILE;      // 2000 blocks

    if (n4 % TILE == 0) {
        hinge_stage1_exact<<<grid, BLOCK, 0, stream>>>(
            (const float4*)outputs, (const float4*)labels, partials);
    } else {
        hinge_stage1_guarded<<<grid, BLOCK, 0, stream>>>(
            (const float4*)outputs, (const float4*)labels, partials, n4);
    }
    hinge_stage2_kernel<<<1, BLOCK, 0, stream>>>(partials, loss, grid, inv_b);
}